// Round 14
// baseline (267.851 us; speedup 1.0000x reference)
//
#include <hip/hip_runtime.h>
#include <hip/hip_bf16.h>

// out[B,S,D_OUT] = x @ sign(W)^T + bias  ==  GEMM M=8192, N=4096, K=4096.
// Round 14: R13 + split ph3's monolithic LGKM0 (a47 certification) into
// LGKM(4) + LGKM(0) around Q3's two 8-MFMA halves — the same counted-lgkm
// sub-batch mechanism that won in R13's ph1/ph2. Everything else identical.

#define M_DIM 8192
#define N_DIM 4096
#define K_DIM 4096
#define BM 256
#define BN 256
#define BK 64
#define NT (K_DIM / BK)  // 64

typedef __attribute__((ext_vector_type(8))) short bf16x8;
typedef __attribute__((ext_vector_type(4))) float f32x4;
typedef __attribute__((ext_vector_type(8))) unsigned short u16x8;

// ---------- conversion helpers ----------

__device__ __forceinline__ unsigned short f2bf_rne(float f) {
    unsigned u = __float_as_uint(f);
    unsigned r = (u + 0x7FFFu + ((u >> 16) & 1u)) >> 16;
    return (unsigned short)r;
}

__device__ __forceinline__ unsigned short sign_bf(float f) {
    if (f == 0.0f) return 0;
    return (unsigned short)(0x3F80u | ((__float_as_uint(f) >> 16) & 0x8000u));
}

// Merged conversion: vec-index < nvec8_x -> bf16 cast of x; else sign(w).
__global__ __launch_bounds__(256) void cvt_both_kernel(
    const float* __restrict__ x, const float* __restrict__ wgt,
    unsigned short* __restrict__ xb, unsigned short* __restrict__ wb,
    long nvec8_x, long nvec8_total) {
    long i = (long)blockIdx.x * blockDim.x + threadIdx.x;
    if (i >= nvec8_total) return;
    if (i < nvec8_x) {
        const float4* p = reinterpret_cast<const float4*>(x) + i * 2;
        float4 v0 = p[0];
        float4 v1 = p[1];
        u16x8 r;
        r[0] = f2bf_rne(v0.x); r[1] = f2bf_rne(v0.y);
        r[2] = f2bf_rne(v0.z); r[3] = f2bf_rne(v0.w);
        r[4] = f2bf_rne(v1.x); r[5] = f2bf_rne(v1.y);
        r[6] = f2bf_rne(v1.z); r[7] = f2bf_rne(v1.w);
        reinterpret_cast<u16x8*>(xb)[i] = r;
    } else {
        long j = i - nvec8_x;
        const float4* p = reinterpret_cast<const float4*>(wgt) + j * 2;
        float4 v0 = p[0];
        float4 v1 = p[1];
        u16x8 r;
        r[0] = sign_bf(v0.x); r[1] = sign_bf(v0.y);
        r[2] = sign_bf(v0.z); r[3] = sign_bf(v0.w);
        r[4] = sign_bf(v1.x); r[5] = sign_bf(v1.y);
        r[6] = sign_bf(v1.z); r[7] = sign_bf(v1.w);
        reinterpret_cast<u16x8*>(wb)[j] = r;
    }
}

// ---------- async global->LDS ----------

__device__ __forceinline__ void GL16(const unsigned short* g, unsigned short* l) {
    __builtin_amdgcn_global_load_lds(
        (const __attribute__((address_space(1))) unsigned int*)g,
        (__attribute__((address_space(3))) unsigned int*)l, 16, 0, 0);
}

// ---------- inline-asm ds_read_b128 with immediate byte offset ----------

template<int OFS>
__device__ __forceinline__ bf16x8 DSR(const unsigned short* p) {
    bf16x8 r;
    auto lp = (const __attribute__((address_space(3))) unsigned short*)p;
    asm volatile("ds_read_b128 %0, %1 offset:%2"
                 : "=&v"(r) : "v"(lp), "i"(OFS));
    return r;
}

#define BARRIER asm volatile("s_barrier" ::: "memory")
#define VMCNT0  asm volatile("s_waitcnt vmcnt(0)" ::: "memory")
#define VMCNT2  asm volatile("s_waitcnt vmcnt(2)" ::: "memory")
#define VMCNT6  asm volatile("s_waitcnt vmcnt(6)" ::: "memory")
#define LGKM0   asm volatile("s_waitcnt lgkmcnt(0)" ::: "memory")
#define LGKM4   asm volatile("s_waitcnt lgkmcnt(4)" ::: "memory")
#define SCHED0  __builtin_amdgcn_sched_barrier(0)
#define PRIO1   __builtin_amdgcn_s_setprio(1)
#define PRIO0   __builtin_amdgcn_s_setprio(0)

// 16-MFMA quadrant: 4 m-frags x 2 n-frags x 2 k-halves
#define CELL(MB, NB, Aa, Bb) \
    _Pragma("unroll") for (int m_ = 0; m_ < 4; ++m_) \
    _Pragma("unroll") for (int n_ = 0; n_ < 2; ++n_) \
    _Pragma("unroll") for (int kk_ = 0; kk_ < 2; ++kk_) \
        acc[(MB) + m_][(NB) + n_] = __builtin_amdgcn_mfma_f32_16x16x32_bf16( \
            Aa[m_][kk_], Bb[n_][kk_], acc[(MB) + m_][(NB) + n_], 0, 0, 0)

// 8-MFMA half-quadrant: 2 m-frags (AOFS..AOFS+1) x 2 n-frags x 2 k-halves
#define HCELL(MB, NB, Aa, AOFS, Bb) \
    _Pragma("unroll") for (int m_ = 0; m_ < 2; ++m_) \
    _Pragma("unroll") for (int n_ = 0; n_ < 2; ++n_) \
    _Pragma("unroll") for (int kk_ = 0; kk_ < 2; ++kk_) \
        acc[(MB) + m_][(NB) + n_] = __builtin_amdgcn_mfma_f32_16x16x32_bf16( \
            Aa[(AOFS) + m_][kk_], Bb[n_][kk_], acc[(MB) + m_][(NB) + n_], 0, 0, 0)

// ---------- 256x256 4-phase GEMM (R13 + ph3 split wait) ----------
// Per K-tile t (CUR=t&1):
//  ph1: bar | stage B23(t+1) | rd a03 x8 | LGKM(4) [b01+a03(0,1)]
//       | 8 MFMA | LGKM(0) | 8 MFMA | rd b23 x4
//  ph2: bar | stage A(t+1) | LGKM(0) [b23] | 8 MFMA | rd a47(0,1) x4
//       | 8 MFMA | rd a47(2,3) x4
//  ph3: vmcnt(6) | bar | LGKM(4) [a47(0,1); entry=8] | 8 MFMA | LGKM(0)
//       | 8 MFMA | rd b01(t+1) x4
//  ph4: bar | stage B01(t+2) | Q4 16 MFMA | vmcnt(s2?2:0)
// vmcnt ledger identical to R12/R13 (proven).

__global__ __launch_bounds__(512, 2) void gemm256j(
    const unsigned short* __restrict__ A,   // [M][K] bf16 bits
    const unsigned short* __restrict__ Bt,  // [N][K] bf16 bits (sign weights)
    const float* __restrict__ bias,         // [N]
    float* __restrict__ C)                  // [M][N] fp32
{
    __shared__ __align__(16) unsigned short As[2][BM * BK];  // 64 KiB
    __shared__ __align__(16) unsigned short Bs[2][BN * BK];  // 64 KiB

    const int tid  = threadIdx.x;
    const int lane = tid & 63;
    const int w    = tid >> 6;
    const int wr   = w >> 2;
    const int wc   = w & 3;

    // T1: XCD-aware bijective swizzle (grid = 512, divisible by 8)
    int bid = blockIdx.x;
    const int cpx = gridDim.x >> 3;
    bid = (bid & 7) * cpx + (bid >> 3);
    const int ntile = N_DIM / BN;  // 16
    const long brow = (long)(bid / ntile) * BM;
    const long bcol = (long)(bid % ntile) * BN;

    // staging lane geometry (inverse-swizzled global src, linear LDS dest)
    const int wrow8 = lane >> 3;
    const int colsw = ((lane & 7) ^ wrow8) * 8;
    const int arw_u = (w >> 2) * 128 + (w & 3) * 8;
    const int brw_u = (w >> 2) * 64 + (w & 3) * 8;
    const long aRow = brow + arw_u + wrow8;
    const long bRow = bcol + brw_u + wrow8;

#define GA(BUF, I, KT) GL16(A  + (aRow + (I) * 32) * (long)K_DIM + (colsw + (KT)), \
                            &As[BUF][(arw_u + (I) * 32) * 64])
#define GB(BUF, OFS, KT) GL16(Bt + (bRow + (OFS)) * (long)K_DIM + (colsw + (KT)), \
                              &Bs[BUF][(brw_u + (OFS)) * 64])

    // fragment read bases (swizzled), loop-invariant
    const int fr = lane & 15;
    const int fq = lane >> 4;
    const int rqu = (fq * 8) ^ ((lane & 7) << 3);
    const int aoff = (wr * 128 + fr) * 64 + rqu;
    const int boff = (wc * 64 + fr) * 64 + rqu;

    const unsigned short* As0k0 = &As[0][aoff];
    const unsigned short* As0k1 = &As[0][aoff ^ 32];
    const unsigned short* As1k0 = &As[1][aoff];
    const unsigned short* As1k1 = &As[1][aoff ^ 32];
    const unsigned short* Bs0k0 = &Bs[0][boff];
    const unsigned short* Bs0k1 = &Bs[0][boff ^ 32];
    const unsigned short* Bs1k0 = &Bs[1][boff];
    const unsigned short* Bs1k1 = &Bs[1][boff ^ 32];

    f32x4 acc[8][4];
#pragma unroll
    for (int m = 0; m < 8; ++m)
#pragma unroll
        for (int n = 0; n < 4; ++n) acc[m][n] = (f32x4){0.f, 0.f, 0.f, 0.f};

    bf16x8 a03[4][2], a47[4][2], b01[2][2], b23[2][2];

    // ----- prologue: tile0 (8 GL16 -> buf0) + tile1's B01 (2 -> buf1) -----
    GA(0, 0, 0); GA(0, 1, 0); GA(0, 2, 0); GA(0, 3, 0);
    GB(0, 0, 0); GB(0, 128, 0); GB(0, 32, 0); GB(0, 160, 0);
    GB(1, 0, BK); GB(1, 128, BK);
    VMCNT0;
    BARRIER;
    // pre-issue b01(t=0); certified at ph1(0)'s LGKM(4)
    b01[0][0] = DSR<0>(Bs0k0);    b01[0][1] = DSR<0>(Bs0k1);
    b01[1][0] = DSR<2048>(Bs0k0); b01[1][1] = DSR<2048>(Bs0k1);

#define TILE_BODY(TT, CUR, NXT, pAc0, pAc1, pBc0, pBc1, pBn0, pBn1) { \
    const long kt1 = (long)((TT) + 1) * BK; \
    const long kt2 = (long)((TT) + 2) * BK; \
    const bool s1 = ((TT) + 1 < NT); \
    const bool s2 = ((TT) + 2 < NT); \
    /* ---- ph1: a03 reads split LGKM(4)/LGKM(0), MFMA between ---- */ \
    BARRIER; \
    if (s1) { GB(NXT, 32, kt1); GB(NXT, 160, kt1); } \
    a03[0][0] = DSR<0>(pAc0);    a03[0][1] = DSR<0>(pAc1); \
    a03[1][0] = DSR<2048>(pAc0); a03[1][1] = DSR<2048>(pAc1); \
    a03[2][0] = DSR<4096>(pAc0); a03[2][1] = DSR<4096>(pAc1); \
    a03[3][0] = DSR<6144>(pAc0); a03[3][1] = DSR<6144>(pAc1); \
    LGKM4; SCHED0; \
    PRIO1; HCELL(0, 0, a03, 0, b01); PRIO0; SCHED0; \
    LGKM0; SCHED0; \
    PRIO1; HCELL(2, 0, a03, 2, b01); PRIO0; SCHED0; \
    b23[0][0] = DSR<4096>(pBc0); b23[0][1] = DSR<4096>(pBc1); \
    b23[1][0] = DSR<6144>(pBc0); b23[1][1] = DSR<6144>(pBc1); \
    /* ---- ph2: a47 reads interleaved inside the CELL ---- */ \
    BARRIER; \
    if (s1) { GA(NXT, 0, kt1); GA(NXT, 1, kt1); GA(NXT, 2, kt1); GA(NXT, 3, kt1); } \
    LGKM0; SCHED0; \
    PRIO1; HCELL(0, 2, a03, 0, b23); PRIO0; SCHED0; \
    a47[0][0] = DSR<8192>(pAc0);  a47[0][1] = DSR<8192>(pAc1); \
    a47[1][0] = DSR<10240>(pAc0); a47[1][1] = DSR<10240>(pAc1); \
    SCHED0; \
    PRIO1; HCELL(2, 2, a03, 2, b23); PRIO0; SCHED0; \
    a47[2][0] = DSR<12288>(pAc0); a47[2][1] = DSR<12288>(pAc1); \
    a47[3][0] = DSR<14336>(pAc0); a47[3][1] = DSR<14336>(pAc1); \
    /* ---- ph3: split a47 certification LGKM(4)/LGKM(0) around Q3 halves ---- */ \
    VMCNT6; \
    BARRIER; \
    LGKM4; SCHED0; \
    PRIO1; HCELL(4, 0, a47, 0, b01); PRIO0; SCHED0; \
    LGKM0; SCHED0; \
    PRIO1; HCELL(6, 0, a47, 2, b01); PRIO0; SCHED0; \
    if (s1) { \
        b01[0][0] = DSR<0>(pBn0);    b01[0][1] = DSR<0>(pBn1); \
        b01[1][0] = DSR<2048>(pBn0); b01[1][1] = DSR<2048>(pBn1); \
    } \
    /* ---- ph4 ---- */ \
    BARRIER; \
    if (s2) { GB(CUR, 0, kt2); GB(CUR, 128, kt2); } \
    PRIO1; CELL(4, 2, a47, b23); PRIO0; SCHED0; \
    /* confirm B23+A[t+1] for ph1(t+1); leave B01[t+2] in flight */ \
    if (s2) { VMCNT2; } else { VMCNT0; } \
}

    for (int t = 0; t < NT; t += 2) {
        TILE_BODY(t,     0, 1, As0k0, As0k1, Bs0k0, Bs0k1, Bs1k0, Bs1k1);
        TILE_BODY(t + 1, 1, 0, As1k0, As1k1, Bs1k0, Bs1k1, Bs0k0, Bs0k1);
    }
#undef TILE_BODY

    // ----- epilogue: C/D layout col = lane&15, row = (lane>>4)*4 + j -----
#pragma unroll
    for (int n = 0; n < 4; ++n) {
        const long cg = bcol + wc * 64 + n * 16 + fr;
        const float bv = bias[cg];
#pragma unroll
        for (int m = 0; m < 8; ++m) {
            const long rbase = brow + wr * 128 + m * 16 + fq * 4;
#pragma unroll
            for (int j = 0; j < 4; ++j)
                C[(rbase + j) * (long)N_DIM + cg] = acc[m][n][j] + bv;
        }
    }
}

// ---------- naive fallback ----------

__global__ __launch_bounds__(256) void naive_kernel(
    const float* __restrict__ x, const float* __restrict__ w,
    const float* __restrict__ bias, float* __restrict__ out, long total) {
    long gid = (long)blockIdx.x * blockDim.x + threadIdx.x;
    if (gid >= total) return;
    long m = gid / N_DIM, n = gid % N_DIM;
    const float* xr = x + m * (long)K_DIM;
    const float* wr = w + n * (long)K_DIM;
    float s = 0.f;
    for (int k = 0; k < K_DIM; ++k) {
        float wv = wr[k];
        float sg = (wv > 0.f) ? 1.f : ((wv < 0.f) ? -1.f : 0.f);
        s += xr[k] * sg;
    }
    out[gid] = s + bias[n];
}

// ---------- launch ----------

extern "C" void kernel_launch(void* const* d_in, const int* in_sizes, int n_in,
                              void* d_out, int out_size, void* d_ws, size_t ws_size,
                              hipStream_t stream) {
    const float* x    = (const float*)d_in[0];
    const float* w    = (const float*)d_in[1];
    const float* bias = (const float*)d_in[2];
    float* out = (float*)d_out;

    const size_t nA = (size_t)M_DIM * K_DIM;
    const size_t nB = (size_t)N_DIM * K_DIM;
    const size_t need_bytes = (nA + nB) * sizeof(unsigned short);

    if (ws_size >= need_bytes) {
        unsigned short* xb = (unsigned short*)d_ws;
        unsigned short* wb = xb + nA;
        {
            long nvec8_x = (long)(nA / 8);
            long nvec8_total = (long)((nA + nB) / 8);
            int blocks = (int)((nvec8_total + 255) / 256);
            cvt_both_kernel<<<blocks, 256, 0, stream>>>(x, w, xb, wb,
                                                        nvec8_x, nvec8_total);
        }
        dim3 grid((M_DIM / BM) * (N_DIM / BN));  // 512
        gemm256j<<<grid, 512, 0, stream>>>(xb, wb, bias, out);
    } else {
        long total = (long)M_DIM * N_DIM;
        naive_kernel<<<(int)((total + 255) / 256), 256, 0, stream>>>(x, w, bias, out, total);
    }
}

// Round 15
// 266.552 us; speedup vs baseline: 1.0049x; 1.0049x over previous
//
#include <hip/hip_runtime.h>
#include <hip/hip_bf16.h>

// out[B,S,D_OUT] = x @ sign(W)^T + bias  ==  GEMM M=8192, N=4096, K=4096.
// Round 15: R13 schedule ported to mfma_f32_32x32x16_bf16 (256 instr x 8.07cy
// = 2066 cyc/tile vs 512 x 4.85 = 2484 — 17% less MFMA-pipe time, same FLOPs).
// Port is isomorphic: read batches (8/8/4/4), quadrant dep-graph, lgkm/vmcnt
// ledgers, staging, and XOR swizzle unchanged. New: 32x32 fragment addressing
// (row=lane&31, k=(lane>>5)*8), ks-slice XOR pointer offsets (32/64/96B),
// C/D layout col=lane&31, row=(reg&3)+8*(reg>>2)+4*(lane>>5) [m74/m101].

#define M_DIM 8192
#define N_DIM 4096
#define K_DIM 4096
#define BM 256
#define BN 256
#define BK 64
#define NT (K_DIM / BK)  // 64

typedef __attribute__((ext_vector_type(8))) short bf16x8;
typedef __attribute__((ext_vector_type(16))) float f32x16;
typedef __attribute__((ext_vector_type(8))) unsigned short u16x8;

// ---------- conversion helpers ----------

__device__ __forceinline__ unsigned short f2bf_rne(float f) {
    unsigned u = __float_as_uint(f);
    unsigned r = (u + 0x7FFFu + ((u >> 16) & 1u)) >> 16;
    return (unsigned short)r;
}

__device__ __forceinline__ unsigned short sign_bf(float f) {
    if (f == 0.0f) return 0;
    return (unsigned short)(0x3F80u | ((__float_as_uint(f) >> 16) & 0x8000u));
}

// Merged conversion: vec-index < nvec8_x -> bf16 cast of x; else sign(w).
__global__ __launch_bounds__(256) void cvt_both_kernel(
    const float* __restrict__ x, const float* __restrict__ wgt,
    unsigned short* __restrict__ xb, unsigned short* __restrict__ wb,
    long nvec8_x, long nvec8_total) {
    long i = (long)blockIdx.x * blockDim.x + threadIdx.x;
    if (i >= nvec8_total) return;
    if (i < nvec8_x) {
        const float4* p = reinterpret_cast<const float4*>(x) + i * 2;
        float4 v0 = p[0];
        float4 v1 = p[1];
        u16x8 r;
        r[0] = f2bf_rne(v0.x); r[1] = f2bf_rne(v0.y);
        r[2] = f2bf_rne(v0.z); r[3] = f2bf_rne(v0.w);
        r[4] = f2bf_rne(v1.x); r[5] = f2bf_rne(v1.y);
        r[6] = f2bf_rne(v1.z); r[7] = f2bf_rne(v1.w);
        reinterpret_cast<u16x8*>(xb)[i] = r;
    } else {
        long j = i - nvec8_x;
        const float4* p = reinterpret_cast<const float4*>(wgt) + j * 2;
        float4 v0 = p[0];
        float4 v1 = p[1];
        u16x8 r;
        r[0] = sign_bf(v0.x); r[1] = sign_bf(v0.y);
        r[2] = sign_bf(v0.z); r[3] = sign_bf(v0.w);
        r[4] = sign_bf(v1.x); r[5] = sign_bf(v1.y);
        r[6] = sign_bf(v1.z); r[7] = sign_bf(v1.w);
        reinterpret_cast<u16x8*>(wb)[j] = r;
    }
}

// ---------- async global->LDS ----------

__device__ __forceinline__ void GL16(const unsigned short* g, unsigned short* l) {
    __builtin_amdgcn_global_load_lds(
        (const __attribute__((address_space(1))) unsigned int*)g,
        (__attribute__((address_space(3))) unsigned int*)l, 16, 0, 0);
}

// ---------- inline-asm ds_read_b128 with immediate byte offset ----------

template<int OFS>
__device__ __forceinline__ bf16x8 DSR(const unsigned short* p) {
    bf16x8 r;
    auto lp = (const __attribute__((address_space(3))) unsigned short*)p;
    asm volatile("ds_read_b128 %0, %1 offset:%2"
                 : "=&v"(r) : "v"(lp), "i"(OFS));
    return r;
}

// XOR on the low 7 bits of an LDS byte address (ks-slice swizzle step).
__device__ __forceinline__ const unsigned short* XP(const unsigned short* p, unsigned x) {
    return (const unsigned short*)((unsigned long long)p ^ x);
}

// Read one operand-tile's 4 k-slices (phys chunk = (2ks+fq32)^e -> base^{0,32,64,96}).
#define READ4(DST, P, OFS) do { \
    (DST)[0] = DSR<(OFS)>(P); \
    (DST)[1] = DSR<(OFS)>(XP((P), 32)); \
    (DST)[2] = DSR<(OFS)>(XP((P), 64)); \
    (DST)[3] = DSR<(OFS)>(XP((P), 96)); } while (0)

#define BARRIER asm volatile("s_barrier" ::: "memory")
#define VMCNT0  asm volatile("s_waitcnt vmcnt(0)" ::: "memory")
#define VMCNT2  asm volatile("s_waitcnt vmcnt(2)" ::: "memory")
#define VMCNT6  asm volatile("s_waitcnt vmcnt(6)" ::: "memory")
#define LGKM0   asm volatile("s_waitcnt lgkmcnt(0)" ::: "memory")
#define LGKM4   asm volatile("s_waitcnt lgkmcnt(4)" ::: "memory")
#define SCHED0  __builtin_amdgcn_sched_barrier(0)
#define PRIO1   __builtin_amdgcn_s_setprio(1)
#define PRIO0   __builtin_amdgcn_s_setprio(0)

// 4-MFMA quarter: one 32x32 output tile x 4 k-slices (K=64)
#define HQ(MT, NTT, AF, BF) \
    _Pragma("unroll") for (int ks_ = 0; ks_ < 4; ++ks_) \
        acc[MT][NTT] = __builtin_amdgcn_mfma_f32_32x32x16_bf16( \
            (AF)[ks_], (BF)[ks_], acc[MT][NTT], 0, 0, 0)

// ---------- 256x256 4-phase GEMM (R13 ledgers, 32x32x16 MFMA) ----------
// 512 thr = 8 waves (2M x 4N); wave out 128x64 = 4 m-tiles x 2 n-tiles of
// 32x32, acc[4][2] f32x16 (128 regs, same as before).
// Batches: am01 = m-tiles 0,1 (8 reads) ; am23 = m-tiles 2,3 (8) ;
//          bn0 = n-tile 0 (4) ; bn1 = n-tile 1 (4).   [= a03/a47/b01/b23]
// Per K-tile t (CUR=t&1):
//  ph1: bar | stage B23(t+1) | rd am01 x8 | LGKM(4) [bn0+m0] | 4 MFMA m0n0
//       | LGKM(0) | 4 MFMA m1n0 | rd bn1 x4
//  ph2: bar | stage A(t+1) | LGKM(0) [bn1] | 4 MFMA m0n1 | rd am23[0] x4
//       | 4 MFMA m1n1 | rd am23[1] x4
//  ph3: vmcnt(6) | bar | LGKM(4) [m2] | 4 MFMA m2n0 | LGKM(0) | 4 MFMA m3n0
//       | rd bn0(t+1) x4
//  ph4: bar | stage B01(t+2) | 8 MFMA m23n1 | vmcnt(s2?2:0)
// vmcnt ledger identical to R12/R13 (staging ops unchanged).

__global__ __launch_bounds__(512, 2) void gemm256k(
    const unsigned short* __restrict__ A,   // [M][K] bf16 bits
    const unsigned short* __restrict__ Bt,  // [N][K] bf16 bits (sign weights)
    const float* __restrict__ bias,         // [N]
    float* __restrict__ C)                  // [M][N] fp32
{
    __shared__ __align__(16) unsigned short As[2][BM * BK];  // 64 KiB
    __shared__ __align__(16) unsigned short Bs[2][BN * BK];  // 64 KiB

    const int tid  = threadIdx.x;
    const int lane = tid & 63;
    const int w    = tid >> 6;
    const int wr   = w >> 2;
    const int wc   = w & 3;

    // T1: XCD-aware bijective swizzle (grid = 512, divisible by 8)
    int bid = blockIdx.x;
    const int cpx = gridDim.x >> 3;
    bid = (bid & 7) * cpx + (bid >> 3);
    const int ntile = N_DIM / BN;  // 16
    const long brow = (long)(bid / ntile) * BM;
    const long bcol = (long)(bid % ntile) * BN;

    // staging lane geometry (inverse-swizzled global src, linear LDS dest)
    const int wrow8 = lane >> 3;
    const int colsw = ((lane & 7) ^ wrow8) * 8;
    const int arw_u = (w >> 2) * 128 + (w & 3) * 8;
    const int brw_u = (w >> 2) * 64 + (w & 3) * 8;
    const long aRow = brow + arw_u + wrow8;
    const long bRow = bcol + brw_u + wrow8;

#define GA(BUF, I, KT) GL16(A  + (aRow + (I) * 32) * (long)K_DIM + (colsw + (KT)), \
                            &As[BUF][(arw_u + (I) * 32) * 64])
#define GB(BUF, OFS, KT) GL16(Bt + (bRow + (OFS)) * (long)K_DIM + (colsw + (KT)), \
                              &Bs[BUF][(brw_u + (OFS)) * 64])

    // 32x32 fragment read bases: lane holds row (lane&31), k = (lane>>5)*8+j.
    // phys 16B-chunk for slice ks: (2ks + fq32) ^ (lane&7); ks=0 base + XOR.
    const int fr32 = lane & 31;
    const int fq32 = lane >> 5;
    const int ch0  = fq32 ^ (lane & 7);
    const int aofs = (wr * 128 + fr32) * 64 + ch0 * 8;
    const int bofs = (wc * 64 + fr32) * 64 + ch0 * 8;

    const unsigned short* A0 = &As[0][aofs];
    const unsigned short* A1 = &As[1][aofs];
    const unsigned short* B0 = &Bs[0][bofs];
    const unsigned short* B1 = &Bs[1][bofs];

    f32x16 acc[4][2];
#pragma unroll
    for (int mt = 0; mt < 4; ++mt)
#pragma unroll
        for (int nt = 0; nt < 2; ++nt)
#pragma unroll
            for (int i2 = 0; i2 < 16; ++i2) acc[mt][nt][i2] = 0.f;

    bf16x8 am01[2][4], am23[2][4], bn0[4], bn1[4];

    // ----- prologue: tile0 (8 GL16 -> buf0) + tile1's B01 (2 -> buf1) -----
    GA(0, 0, 0); GA(0, 1, 0); GA(0, 2, 0); GA(0, 3, 0);
    GB(0, 0, 0); GB(0, 128, 0); GB(0, 32, 0); GB(0, 160, 0);
    GB(1, 0, BK); GB(1, 128, BK);
    VMCNT0;
    BARRIER;
    READ4(bn0, B0, 0);  // n-tile 0 of t=0; certified at ph1(0)'s LGKM(4)

#define TILE_BODY(TT, CUR, NXT, PA, PB, PBn) { \
    const long kt1 = (long)((TT) + 1) * BK; \
    const long kt2 = (long)((TT) + 2) * BK; \
    const bool s1 = ((TT) + 1 < NT); \
    const bool s2 = ((TT) + 2 < NT); \
    /* ---- ph1 ---- */ \
    BARRIER; \
    if (s1) { GB(NXT, 32, kt1); GB(NXT, 160, kt1); } \
    READ4(am01[0], PA, 0); \
    READ4(am01[1], PA, 4096); \
    LGKM4; SCHED0; \
    PRIO1; HQ(0, 0, am01[0], bn0); PRIO0; SCHED0; \
    LGKM0; SCHED0; \
    PRIO1; HQ(1, 0, am01[1], bn0); PRIO0; SCHED0; \
    READ4(bn1, PB, 4096); \
    /* ---- ph2 ---- */ \
    BARRIER; \
    if (s1) { GA(NXT, 0, kt1); GA(NXT, 1, kt1); GA(NXT, 2, kt1); GA(NXT, 3, kt1); } \
    LGKM0; SCHED0; \
    PRIO1; HQ(0, 1, am01[0], bn1); PRIO0; SCHED0; \
    READ4(am23[0], PA, 8192); \
    SCHED0; \
    PRIO1; HQ(1, 1, am01[1], bn1); PRIO0; SCHED0; \
    READ4(am23[1], PA, 12288); \
    /* ---- ph3: counted drain (B01[t+1] confirmed; B23/A[t+1] in flight) ---- */ \
    VMCNT6; \
    BARRIER; \
    LGKM4; SCHED0; \
    PRIO1; HQ(2, 0, am23[0], bn0); PRIO0; SCHED0; \
    LGKM0; SCHED0; \
    PRIO1; HQ(3, 0, am23[1], bn0); PRIO0; SCHED0; \
    if (s1) { READ4(bn0, PBn, 0); } \
    /* ---- ph4 ---- */ \
    BARRIER; \
    if (s2) { GB(CUR, 0, kt2); GB(CUR, 128, kt2); } \
    PRIO1; HQ(2, 1, am23[0], bn1); HQ(3, 1, am23[1], bn1); PRIO0; SCHED0; \
    /* confirm B23+A[t+1] for ph1(t+1); leave B01[t+2] in flight */ \
    if (s2) { VMCNT2; } else { VMCNT0; } \
}

    for (int t = 0; t < NT; t += 2) {
        TILE_BODY(t,     0, 1, A0, B0, B1);
        TILE_BODY(t + 1, 1, 0, A1, B1, B0);
    }
#undef TILE_BODY

    // ----- epilogue: 32x32 C/D layout: col = lane&31,
    //       row = (reg&3) + 8*(reg>>2) + 4*(lane>>5)  [m74/m101] -----
#pragma unroll
    for (int nt = 0; nt < 2; ++nt) {
        const long cg = bcol + wc * 64 + nt * 32 + fr32;
        const float bv = bias[cg];
#pragma unroll
        for (int mt = 0; mt < 4; ++mt) {
            const long rbase = brow + wr * 128 + mt * 32 + fq32 * 4;
#pragma unroll
            for (int r = 0; r < 16; ++r) {
                const long row = rbase + (r & 3) + 8 * (r >> 2);
                C[row * (long)N_DIM + cg] = acc[mt][nt][r] + bv;
            }
        }
    }
}

// ---------- naive fallback ----------

__global__ __launch_bounds__(256) void naive_kernel(
    const float* __restrict__ x, const float* __restrict__ w,
    const float* __restrict__ bias, float* __restrict__ out, long total) {
    long gid = (long)blockIdx.x * blockDim.x + threadIdx.x;
    if (gid >= total) return;
    long m = gid / N_DIM, n = gid % N_DIM;
    const float* xr = x + m * (long)K_DIM;
    const float* wr = w + n * (long)K_DIM;
    float s = 0.f;
    for (int k = 0; k < K_DIM; ++k) {
        float wv = wr[k];
        float sg = (wv > 0.f) ? 1.f : ((wv < 0.f) ? -1.f : 0.f);
        s += xr[k] * sg;
    }
    out[gid] = s + bias[n];
}

// ---------- launch ----------

extern "C" void kernel_launch(void* const* d_in, const int* in_sizes, int n_in,
                              void* d_out, int out_size, void* d_ws, size_t ws_size,
                              hipStream_t stream) {
    const float* x    = (const float*)d_in[0];
    const float* w    = (const float*)d_in[1];
    const float* bias = (const float*)d_in[2];
    float* out = (float*)d_out;

    const size_t nA = (size_t)M_DIM * K_DIM;
    const size_t nB = (size_t)N_DIM * K_DIM;
    const size_t need_bytes = (nA + nB) * sizeof(unsigned short);

    if (ws_size >= need_bytes) {
        unsigned short* xb = (unsigned short*)d_ws;
        unsigned short* wb = xb + nA;
        {
            long nvec8_x = (long)(nA / 8);
            long nvec8_total = (long)((nA + nB) / 8);
            int blocks = (int)((nvec8_total + 255) / 256);
            cvt_both_kernel<<<blocks, 256, 0, stream>>>(x, w, xb, wb,
                                                        nvec8_x, nvec8_total);
        }
        dim3 grid((M_DIM / BM) * (N_DIM / BN));  // 512
        gemm256k<<<grid, 512, 0, stream>>>(xb, wb, bias, out);
    } else {
        long total = (long)M_DIM * N_DIM;
        naive_kernel<<<(int)((total + 255) / 256), 256, 0, stream>>>(x, w, bias, out, total);
    }
}

// Round 17
// 181.979 us; speedup vs baseline: 1.4719x; 1.4647x over previous
//
#include <hip/hip_runtime.h>
#include <hip/hip_bf16.h>

// out[B,S,D_OUT] = x @ sign(W)^T + bias  ==  GEMM M=8192, N=4096, K=4096.
// Round 17: R16 (int8 pipeline) + one-line bugfix. R16's absmax=336 root
// cause: cvt_x_i8 reduced over red[0..7] but only red[0..3] are written
// (256 thr = 4 waves) -> uninitialized-LDS garbage inflated rmax for some
// rows -> those rows quantized to ~0 -> |err| ~ |ref|. GEMM unchanged.

#define M_DIM 8192
#define N_DIM 4096
#define K_DIM 4096
#define BM 256
#define BN 256
#define BK 64
#define NT (K_DIM / BK)  // 64

typedef __attribute__((ext_vector_type(4))) int i32x4;

// ---------- conversion kernels ----------

__device__ __forceinline__ signed char sgn_i8(float f) {
    return (f > 0.f) ? 1 : ((f < 0.f) ? -1 : 0);
}

// W: f32 -> sign in i8, 16 elems/thread
__global__ __launch_bounds__(256) void cvt_w_i8(
    const float* __restrict__ in, signed char* __restrict__ out, long nvec16) {
    long i = (long)blockIdx.x * blockDim.x + threadIdx.x;
    if (i >= nvec16) return;
    const float4* p = reinterpret_cast<const float4*>(in) + i * 4;
    int4 r;
    signed char* rc = (signed char*)&r;
#pragma unroll
    for (int k = 0; k < 4; ++k) {
        float4 v = p[k];
        rc[k * 4 + 0] = sgn_i8(v.x);
        rc[k * 4 + 1] = sgn_i8(v.y);
        rc[k * 4 + 2] = sgn_i8(v.z);
        rc[k * 4 + 3] = sgn_i8(v.w);
    }
    reinterpret_cast<int4*>(out)[i] = r;
}

// x: per-row absmax + quantize to i8. One block (256 thr = 4 waves) per row.
__global__ __launch_bounds__(256) void cvt_x_i8(
    const float* __restrict__ x, signed char* __restrict__ q,
    float* __restrict__ scales) {
    const int row = blockIdx.x;
    const int tid = threadIdx.x;
    const float4* xr4 = reinterpret_cast<const float4*>(x + (long)row * K_DIM);
    __shared__ float red[4];

    float mx = 0.f;
#pragma unroll
    for (int i = 0; i < 4; ++i) {
        float4 v = xr4[tid + i * 256];
        mx = fmaxf(mx, fmaxf(fmaxf(fabsf(v.x), fabsf(v.y)),
                             fmaxf(fabsf(v.z), fabsf(v.w))));
    }
#pragma unroll
    for (int o = 1; o < 64; o <<= 1) mx = fmaxf(mx, __shfl_xor(mx, o));
    if ((tid & 63) == 0) red[tid >> 6] = mx;
    __syncthreads();
    // FIX (R16 bug): 4 waves -> only red[0..3] are valid.
    float rmax = fmaxf(fmaxf(red[0], red[1]), fmaxf(red[2], red[3]));
    const float inv = (rmax > 0.f) ? (127.f / rmax) : 0.f;

    char4* qr = reinterpret_cast<char4*>(q + (long)row * K_DIM);
#pragma unroll
    for (int i = 0; i < 4; ++i) {
        float4 v = xr4[tid + i * 256];
        char4 c;
        c.x = (signed char)__float2int_rn(fminf(fmaxf(v.x * inv, -127.f), 127.f));
        c.y = (signed char)__float2int_rn(fminf(fmaxf(v.y * inv, -127.f), 127.f));
        c.z = (signed char)__float2int_rn(fminf(fmaxf(v.z * inv, -127.f), 127.f));
        c.w = (signed char)__float2int_rn(fminf(fmaxf(v.w * inv, -127.f), 127.f));
        qr[tid + i * 256] = c;
    }
    if (tid == 0) scales[row] = (rmax > 0.f) ? (rmax * (1.f / 127.f)) : 0.f;
}

// ---------- async global->LDS ----------

__device__ __forceinline__ void GL16(const void* g, void* l) {
    __builtin_amdgcn_global_load_lds(
        (const __attribute__((address_space(1))) unsigned int*)g,
        (__attribute__((address_space(3))) unsigned int*)l, 16, 0, 0);
}

// ---------- inline-asm ds_read_b128 (i32x4) ----------

template<int OFS>
__device__ __forceinline__ i32x4 DSRI(const signed char* p) {
    i32x4 r;
    auto lp = (const __attribute__((address_space(3))) signed char*)p;
    asm volatile("ds_read_b128 %0, %1 offset:%2"
                 : "=&v"(r) : "v"(lp), "i"(OFS));
    return r;
}

#define BARRIER asm volatile("s_barrier" ::: "memory")
#define VMCNT0  asm volatile("s_waitcnt vmcnt(0)" ::: "memory")
#define VMCNT1  asm volatile("s_waitcnt vmcnt(1)" ::: "memory")
#define VMCNT3  asm volatile("s_waitcnt vmcnt(3)" ::: "memory")
#define LGKM0   asm volatile("s_waitcnt lgkmcnt(0)" ::: "memory")
#define LGKM2   asm volatile("s_waitcnt lgkmcnt(2)" ::: "memory")
#define SCHED0  __builtin_amdgcn_sched_barrier(0)
#define PRIO1   __builtin_amdgcn_s_setprio(1)
#define PRIO0   __builtin_amdgcn_s_setprio(0)

// 4-MFMA cell: 2 m-frags x 2 n-frags, K=64 in one MFMA each.
#define HC(MB, NB, Af, AOFS, Bf) \
    _Pragma("unroll") for (int m_ = 0; m_ < 2; ++m_) \
    _Pragma("unroll") for (int n_ = 0; n_ < 2; ++n_) \
        acc[(MB) + m_][(NB) + n_] = __builtin_amdgcn_mfma_i32_16x16x64_i8( \
            Af[(AOFS) + m_], Bf[n_], acc[(MB) + m_][(NB) + n_], 0, 0, 0)

// ---------- 256x256 4-phase i8 GEMM (R13 ledger, halved counts) ----------
// 512 thr = 8 waves (2M x 4N); wave out 128x64 = 8x4 16x16 frags; 32 MFMA/tile.
// LDS: As/Bs [2][256 rows][64B] = 64 KiB total. Swizzle: row r's logical
// 16B-chunk g stored at phys g ^ ((r>>2)&3); staged via inverse-swizzled
// global source cols (linear GL16 dest), read with the same XOR.
// Per K-tile t (CUR=t&1):
//  ph1: bar | stage B23(t+1)->NXT | rd a03 x4 | LGKM(2) [b01+a03(0,1)]
//       | 4 MFMA | LGKM(0) | 4 MFMA | rd b23 x2
//  ph2: bar | stage A03+A47(t+1)->NXT | LGKM(0) [b23] | 4 MFMA | rd a47(0,1)
//       | 4 MFMA | rd a47(2,3)
//  ph3: vmcnt(3) [confirms B01(t+1)] | bar | LGKM(2) [a47(0,1)] | 4 MFMA
//       | LGKM(0) | 4 MFMA | rd b01(t+1) x2
//  ph4: bar | stage B01(t+2)->CUR | 8 MFMA | vmcnt(s2?1:0)
// vmcnt ledger (in-order): ph3(t): B01[t+1](1)+B23[t+1](1)+A[t+1](2)=4 ->
// vmcnt(3) drains B01[t+1]. ph4(t) end: B23+A[t+1]+B01[t+2]=4 -> vmcnt(1)
// drains B23+A[t+1]. Tail s2=false -> vmcnt(0).

__global__ __launch_bounds__(512, 2) void gemm256q(
    const signed char* __restrict__ A,   // [M][K] i8 (quantized x)
    const signed char* __restrict__ Bt,  // [N][K] i8 (sign weights)
    const float* __restrict__ scales,    // [M] rowmax/127
    const float* __restrict__ bias,      // [N]
    float* __restrict__ C)               // [M][N] fp32
{
    __shared__ __align__(16) signed char As[2][BM * BK];  // 2 x 16 KiB
    __shared__ __align__(16) signed char Bs[2][BN * BK];  // 2 x 16 KiB

    const int tid  = threadIdx.x;
    const int lane = tid & 63;
    const int w    = tid >> 6;
    const int wr   = w >> 2;
    const int wc   = w & 3;

    // T1: XCD-aware bijective swizzle (grid = 512, divisible by 8)
    int bid = blockIdx.x;
    const int cpx = gridDim.x >> 3;
    bid = (bid & 7) * cpx + (bid >> 3);
    const int ntile = N_DIM / BN;  // 16
    const long brow = (long)(bid / ntile) * BM;
    const long bcol = (long)(bid % ntile) * BN;

    // ----- staging: each GL16/wave = 16 rows x 64B; lane l -> row l>>2,
    // phys chunk l&3; global col chunk g = (l&3) ^ ((l>>4)&3) (inverse swz).
    const int lrow  = lane >> 2;
    const int gcol  = ((lane & 3) ^ ((lane >> 4) & 3)) * 16;  // i8 elements
    const int rA03u = (w >> 2) * 128 + (w & 3) * 16;          // wave-uniform
    const int rB01u = (w >> 1) * 64 + (w & 1) * 16;
    const long gA03 = brow + rA03u + lrow;
    const long gB01 = bcol + rB01u + lrow;

#define GA03(BUF, KT) GL16(A  + (gA03)      * (long)K_DIM + (gcol + (KT)), &As[BUF][(rA03u)      * 64])
#define GA47(BUF, KT) GL16(A  + (gA03 + 64) * (long)K_DIM + (gcol + (KT)), &As[BUF][(rA03u + 64) * 64])
#define GB01(BUF, KT) GL16(Bt + (gB01)      * (long)K_DIM + (gcol + (KT)), &Bs[BUF][(rB01u)      * 64])
#define GB23(BUF, KT) GL16(Bt + (gB01 + 32) * (long)K_DIM + (gcol + (KT)), &Bs[BUF][(rB01u + 32) * 64])

    // ----- fragment reads: row = base + (lane&15), k-chunk g = lane>>4,
    // phys chunk = g ^ (((lane&15)>>2)&3) = (lane>>4) ^ ((lane>>2)&3).
    const int fr = lane & 15;
    const int fq = lane >> 4;
    const int pch = (fq ^ ((lane >> 2) & 3)) * 16;  // bytes
    const int aoffB = (wr * 128 + fr) * 64 + pch;
    const int boffB = (wc * 64 + fr) * 64 + pch;

    const signed char* pA0 = &As[0][aoffB];
    const signed char* pA1 = &As[1][aoffB];
    const signed char* pB0 = &Bs[0][boffB];
    const signed char* pB1 = &Bs[1][boffB];

    i32x4 acc[8][4];
#pragma unroll
    for (int m = 0; m < 8; ++m)
#pragma unroll
        for (int n = 0; n < 4; ++n) acc[m][n] = (i32x4){0, 0, 0, 0};

    i32x4 a03[4], a47[4], b01[2], b23[2];

    // ----- prologue: tile0 (4 GL16) + tile1's B01 (1 GL16) -----
    GA03(0, 0); GA47(0, 0); GB01(0, 0); GB23(0, 0);
    GB01(1, BK);
    VMCNT0;
    BARRIER;
    b01[0] = DSRI<0>(pB0);
    b01[1] = DSRI<1024>(pB0);

#define TILE_BODY(TT, CUR, NXT, pAc, pBc, pBn) { \
    const long kt1 = (long)((TT) + 1) * BK; \
    const long kt2 = (long)((TT) + 2) * BK; \
    const bool s1 = ((TT) + 1 < NT); \
    const bool s2 = ((TT) + 2 < NT); \
    /* ---- ph1 ---- */ \
    BARRIER; \
    if (s1) { GB23(NXT, kt1); } \
    a03[0] = DSRI<0>(pAc);    a03[1] = DSRI<1024>(pAc); \
    a03[2] = DSRI<2048>(pAc); a03[3] = DSRI<3072>(pAc); \
    LGKM2; SCHED0; \
    PRIO1; HC(0, 0, a03, 0, b01); PRIO0; SCHED0; \
    LGKM0; SCHED0; \
    PRIO1; HC(2, 0, a03, 2, b01); PRIO0; SCHED0; \
    b23[0] = DSRI<2048>(pBc); b23[1] = DSRI<3072>(pBc); \
    /* ---- ph2 ---- */ \
    BARRIER; \
    if (s1) { GA03(NXT, kt1); GA47(NXT, kt1); } \
    LGKM0; SCHED0; \
    PRIO1; HC(0, 2, a03, 0, b23); PRIO0; SCHED0; \
    a47[0] = DSRI<4096>(pAc); a47[1] = DSRI<5120>(pAc); \
    SCHED0; \
    PRIO1; HC(2, 2, a03, 2, b23); PRIO0; SCHED0; \
    a47[2] = DSRI<6144>(pAc); a47[3] = DSRI<7168>(pAc); \
    /* ---- ph3: counted drain (B01[t+1] confirmed; B23/A[t+1] in flight) */ \
    VMCNT3; \
    BARRIER; \
    LGKM2; SCHED0; \
    PRIO1; HC(4, 0, a47, 0, b01); PRIO0; SCHED0; \
    LGKM0; SCHED0; \
    PRIO1; HC(6, 0, a47, 2, b01); PRIO0; SCHED0; \
    if (s1) { b01[0] = DSRI<0>(pBn); b01[1] = DSRI<1024>(pBn); } \
    /* ---- ph4 ---- */ \
    BARRIER; \
    if (s2) { GB01(CUR, kt2); } \
    PRIO1; HC(4, 2, a47, 0, b23); HC(6, 2, a47, 2, b23); PRIO0; SCHED0; \
    if (s2) { VMCNT1; } else { VMCNT0; } \
}

    for (int t = 0; t < NT; t += 2) {
        TILE_BODY(t,     0, 1, pA0, pB0, pB1);
        TILE_BODY(t + 1, 1, 0, pA1, pB1, pB0);
    }
#undef TILE_BODY

    // ----- epilogue: C/D layout col = lane&15, row = (lane>>4)*4 + j.
    // out = acc_i32 * scale[row] + bias[col]  (acc exact; |acc| < 2^24).
    float bv[4];
#pragma unroll
    for (int n = 0; n < 4; ++n) bv[n] = bias[bcol + wc * 64 + n * 16 + fr];
#pragma unroll
    for (int m = 0; m < 8; ++m) {
        const long rbase = brow + wr * 128 + m * 16 + fq * 4;
        float sc[4];
        *reinterpret_cast<float4*>(sc) =
            *reinterpret_cast<const float4*>(scales + rbase);
#pragma unroll
        for (int n = 0; n < 4; ++n) {
            const long cg = bcol + wc * 64 + n * 16 + fr;
#pragma unroll
            for (int j = 0; j < 4; ++j)
                C[(rbase + j) * (long)N_DIM + cg] =
                    (float)acc[m][n][j] * sc[j] + bv[n];
        }
    }
}

// ---------- naive fallback ----------

__global__ __launch_bounds__(256) void naive_kernel(
    const float* __restrict__ x, const float* __restrict__ w,
    const float* __restrict__ bias, float* __restrict__ out, long total) {
    long gid = (long)blockIdx.x * blockDim.x + threadIdx.x;
    if (gid >= total) return;
    long m = gid / N_DIM, n = gid % N_DIM;
    const float* xr = x + m * (long)K_DIM;
    const float* wr = w + n * (long)K_DIM;
    float s = 0.f;
    for (int k = 0; k < K_DIM; ++k) {
        float wv = wr[k];
        float sg = (wv > 0.f) ? 1.f : ((wv < 0.f) ? -1.f : 0.f);
        s += xr[k] * sg;
    }
    out[gid] = s + bias[n];
}

// ---------- launch ----------

extern "C" void kernel_launch(void* const* d_in, const int* in_sizes, int n_in,
                              void* d_out, int out_size, void* d_ws, size_t ws_size,
                              hipStream_t stream) {
    const float* x    = (const float*)d_in[0];
    const float* w    = (const float*)d_in[1];
    const float* bias = (const float*)d_in[2];
    float* out = (float*)d_out;

    const size_t nA = (size_t)M_DIM * K_DIM;  // 33.5M
    const size_t nB = (size_t)N_DIM * K_DIM;  // 16.8M
    const size_t need = nA + nB + M_DIM * sizeof(float) + 64;

    if (ws_size >= need) {
        signed char* xb = (signed char*)d_ws;
        signed char* wb = xb + nA;
        float* scales = (float*)(wb + nB);

        {
            long nvec16 = (long)(nB / 16);
            cvt_w_i8<<<(int)((nvec16 + 255) / 256), 256, 0, stream>>>(w, wb, nvec16);
        }
        cvt_x_i8<<<M_DIM, 256, 0, stream>>>(x, xb, scales);

        dim3 grid((M_DIM / BM) * (N_DIM / BN));  // 512
        gemm256q<<<grid, 512, 0, stream>>>(xb, wb, scales, bias, out);
    } else {
        long total = (long)M_DIM * N_DIM;
        naive_kernel<<<(int)((total + 255) / 256), 256, 0, stream>>>(x, w, bias, out, total);
    }
}

// Round 18
// 180.194 us; speedup vs baseline: 1.4865x; 1.0099x over previous
//
#include <hip/hip_runtime.h>
#include <hip/hip_bf16.h>

// out[B,S,D_OUT] = x @ sign(W)^T + bias  ==  GEMM M=8192, N=4096, K=4096.
// Round 18: R17 + i8 swizzle fix. R17's 1.26e7 bank conflicts (4/read):
// 64B rows have bank period 2 in row, but the swizzle XORed (row>>2)&3
// (period 4) -> each 8-lane service group covered only 16 banks (2-way).
// Fix: phys_chunk = g ^ ((row>>1)&3) -> every 8-lane group covers all 32
// banks (verified per fq group). Staging inverse: (l&3) ^ ((l>>3)&3).
// Everything else byte-identical to R17 (passing, 137us GEMM).

#define M_DIM 8192
#define N_DIM 4096
#define K_DIM 4096
#define BM 256
#define BN 256
#define BK 64
#define NT (K_DIM / BK)  // 64

typedef __attribute__((ext_vector_type(4))) int i32x4;

// ---------- conversion kernels ----------

__device__ __forceinline__ signed char sgn_i8(float f) {
    return (f > 0.f) ? 1 : ((f < 0.f) ? -1 : 0);
}

// W: f32 -> sign in i8, 16 elems/thread
__global__ __launch_bounds__(256) void cvt_w_i8(
    const float* __restrict__ in, signed char* __restrict__ out, long nvec16) {
    long i = (long)blockIdx.x * blockDim.x + threadIdx.x;
    if (i >= nvec16) return;
    const float4* p = reinterpret_cast<const float4*>(in) + i * 4;
    int4 r;
    signed char* rc = (signed char*)&r;
#pragma unroll
    for (int k = 0; k < 4; ++k) {
        float4 v = p[k];
        rc[k * 4 + 0] = sgn_i8(v.x);
        rc[k * 4 + 1] = sgn_i8(v.y);
        rc[k * 4 + 2] = sgn_i8(v.z);
        rc[k * 4 + 3] = sgn_i8(v.w);
    }
    reinterpret_cast<int4*>(out)[i] = r;
}

// x: per-row absmax + quantize to i8. One block (256 thr = 4 waves) per row.
__global__ __launch_bounds__(256) void cvt_x_i8(
    const float* __restrict__ x, signed char* __restrict__ q,
    float* __restrict__ scales) {
    const int row = blockIdx.x;
    const int tid = threadIdx.x;
    const float4* xr4 = reinterpret_cast<const float4*>(x + (long)row * K_DIM);
    __shared__ float red[4];

    float mx = 0.f;
#pragma unroll
    for (int i = 0; i < 4; ++i) {
        float4 v = xr4[tid + i * 256];
        mx = fmaxf(mx, fmaxf(fmaxf(fabsf(v.x), fabsf(v.y)),
                             fmaxf(fabsf(v.z), fabsf(v.w))));
    }
#pragma unroll
    for (int o = 1; o < 64; o <<= 1) mx = fmaxf(mx, __shfl_xor(mx, o));
    if ((tid & 63) == 0) red[tid >> 6] = mx;
    __syncthreads();
    float rmax = fmaxf(fmaxf(red[0], red[1]), fmaxf(red[2], red[3]));
    const float inv = (rmax > 0.f) ? (127.f / rmax) : 0.f;

    char4* qr = reinterpret_cast<char4*>(q + (long)row * K_DIM);
#pragma unroll
    for (int i = 0; i < 4; ++i) {
        float4 v = xr4[tid + i * 256];
        char4 c;
        c.x = (signed char)__float2int_rn(fminf(fmaxf(v.x * inv, -127.f), 127.f));
        c.y = (signed char)__float2int_rn(fminf(fmaxf(v.y * inv, -127.f), 127.f));
        c.z = (signed char)__float2int_rn(fminf(fmaxf(v.z * inv, -127.f), 127.f));
        c.w = (signed char)__float2int_rn(fminf(fmaxf(v.w * inv, -127.f), 127.f));
        qr[tid + i * 256] = c;
    }
    if (tid == 0) scales[row] = (rmax > 0.f) ? (rmax * (1.f / 127.f)) : 0.f;
}

// ---------- async global->LDS ----------

__device__ __forceinline__ void GL16(const void* g, void* l) {
    __builtin_amdgcn_global_load_lds(
        (const __attribute__((address_space(1))) unsigned int*)g,
        (__attribute__((address_space(3))) unsigned int*)l, 16, 0, 0);
}

// ---------- inline-asm ds_read_b128 (i32x4) ----------

template<int OFS>
__device__ __forceinline__ i32x4 DSRI(const signed char* p) {
    i32x4 r;
    auto lp = (const __attribute__((address_space(3))) signed char*)p;
    asm volatile("ds_read_b128 %0, %1 offset:%2"
                 : "=&v"(r) : "v"(lp), "i"(OFS));
    return r;
}

#define BARRIER asm volatile("s_barrier" ::: "memory")
#define VMCNT0  asm volatile("s_waitcnt vmcnt(0)" ::: "memory")
#define VMCNT1  asm volatile("s_waitcnt vmcnt(1)" ::: "memory")
#define VMCNT3  asm volatile("s_waitcnt vmcnt(3)" ::: "memory")
#define LGKM0   asm volatile("s_waitcnt lgkmcnt(0)" ::: "memory")
#define LGKM2   asm volatile("s_waitcnt lgkmcnt(2)" ::: "memory")
#define SCHED0  __builtin_amdgcn_sched_barrier(0)
#define PRIO1   __builtin_amdgcn_s_setprio(1)
#define PRIO0   __builtin_amdgcn_s_setprio(0)

// 4-MFMA cell: 2 m-frags x 2 n-frags, K=64 in one MFMA each.
#define HC(MB, NB, Af, AOFS, Bf) \
    _Pragma("unroll") for (int m_ = 0; m_ < 2; ++m_) \
    _Pragma("unroll") for (int n_ = 0; n_ < 2; ++n_) \
        acc[(MB) + m_][(NB) + n_] = __builtin_amdgcn_mfma_i32_16x16x64_i8( \
            Af[(AOFS) + m_], Bf[n_], acc[(MB) + m_][(NB) + n_], 0, 0, 0)

// ---------- 256x256 4-phase i8 GEMM (R17 schedule, fixed swizzle) ----------
// 512 thr = 8 waves (2M x 4N); wave out 128x64 = 8x4 16x16 frags; 32 MFMA/tile.
// LDS: As/Bs [2][256 rows][64B] = 64 KiB total (2 blocks/CU co-resident).
// Swizzle: row r's logical 16B-chunk g at phys g ^ ((r>>1)&3); staged via
// inverse-swizzled global cols (linear GL16 dest), read with the same XOR.
// Per K-tile t (CUR=t&1):
//  ph1: bar | stage B23(t+1)->NXT | rd a03 x4 | LGKM(2) [b01+a03(0,1)]
//       | 4 MFMA | LGKM(0) | 4 MFMA | rd b23 x2
//  ph2: bar | stage A03+A47(t+1)->NXT | LGKM(0) [b23] | 4 MFMA | rd a47(0,1)
//       | 4 MFMA | rd a47(2,3)
//  ph3: vmcnt(3) [confirms B01(t+1)] | bar | LGKM(2) [a47(0,1)] | 4 MFMA
//       | LGKM(0) | 4 MFMA | rd b01(t+1) x2
//  ph4: bar | stage B01(t+2)->CUR | 8 MFMA | vmcnt(s2?1:0)
// vmcnt ledger (in-order): ph3(t): B01[t+1](1)+B23[t+1](1)+A[t+1](2)=4 ->
// vmcnt(3) drains B01[t+1]. ph4(t) end: B23+A[t+1]+B01[t+2]=4 -> vmcnt(1)
// drains B23+A[t+1]. Tail s2=false -> vmcnt(0).

__global__ __launch_bounds__(512, 2) void gemm256q(
    const signed char* __restrict__ A,   // [M][K] i8 (quantized x)
    const signed char* __restrict__ Bt,  // [N][K] i8 (sign weights)
    const float* __restrict__ scales,    // [M] rowmax/127
    const float* __restrict__ bias,      // [N]
    float* __restrict__ C)               // [M][N] fp32
{
    __shared__ __align__(16) signed char As[2][BM * BK];  // 2 x 16 KiB
    __shared__ __align__(16) signed char Bs[2][BN * BK];  // 2 x 16 KiB

    const int tid  = threadIdx.x;
    const int lane = tid & 63;
    const int w    = tid >> 6;
    const int wr   = w >> 2;
    const int wc   = w & 3;

    // T1: XCD-aware bijective swizzle (grid = 512, divisible by 8)
    int bid = blockIdx.x;
    const int cpx = gridDim.x >> 3;
    bid = (bid & 7) * cpx + (bid >> 3);
    const int ntile = N_DIM / BN;  // 16
    const long brow = (long)(bid / ntile) * BM;
    const long bcol = (long)(bid % ntile) * BN;

    // ----- staging: each GL16/wave = 16 rows x 64B; lane l -> row l>>2,
    // phys chunk l&3; global col chunk g = (l&3) ^ ((l>>3)&3)  [row>>1 swz].
    const int lrow  = lane >> 2;
    const int gcol  = ((lane & 3) ^ ((lane >> 3) & 3)) * 16;  // i8 elements
    const int rA03u = (w >> 2) * 128 + (w & 3) * 16;          // wave-uniform
    const int rB01u = (w >> 1) * 64 + (w & 1) * 16;
    const long gA03 = brow + rA03u + lrow;
    const long gB01 = bcol + rB01u + lrow;

#define GA03(BUF, KT) GL16(A  + (gA03)      * (long)K_DIM + (gcol + (KT)), &As[BUF][(rA03u)      * 64])
#define GA47(BUF, KT) GL16(A  + (gA03 + 64) * (long)K_DIM + (gcol + (KT)), &As[BUF][(rA03u + 64) * 64])
#define GB01(BUF, KT) GL16(Bt + (gB01)      * (long)K_DIM + (gcol + (KT)), &Bs[BUF][(rB01u)      * 64])
#define GB23(BUF, KT) GL16(Bt + (gB01 + 32) * (long)K_DIM + (gcol + (KT)), &Bs[BUF][(rB01u + 32) * 64])

    // ----- fragment reads: row = base + (lane&15), k-chunk g = lane>>4,
    // phys chunk = g ^ ((row>>1)&3) = (lane>>4) ^ ((lane>>1)&3)  [base%16==0].
    const int fr = lane & 15;
    const int fq = lane >> 4;
    const int pch = (fq ^ ((lane >> 1) & 3)) * 16;  // bytes
    const int aoffB = (wr * 128 + fr) * 64 + pch;
    const int boffB = (wc * 64 + fr) * 64 + pch;

    const signed char* pA0 = &As[0][aoffB];
    const signed char* pA1 = &As[1][aoffB];
    const signed char* pB0 = &Bs[0][boffB];
    const signed char* pB1 = &Bs[1][boffB];

    i32x4 acc[8][4];
#pragma unroll
    for (int m = 0; m < 8; ++m)
#pragma unroll
        for (int n = 0; n < 4; ++n) acc[m][n] = (i32x4){0, 0, 0, 0};

    i32x4 a03[4], a47[4], b01[2], b23[2];

    // ----- prologue: tile0 (4 GL16) + tile1's B01 (1 GL16) -----
    GA03(0, 0); GA47(0, 0); GB01(0, 0); GB23(0, 0);
    GB01(1, BK);
    VMCNT0;
    BARRIER;
    b01[0] = DSRI<0>(pB0);
    b01[1] = DSRI<1024>(pB0);

#define TILE_BODY(TT, CUR, NXT, pAc, pBc, pBn) { \
    const long kt1 = (long)((TT) + 1) * BK; \
    const long kt2 = (long)((TT) + 2) * BK; \
    const bool s1 = ((TT) + 1 < NT); \
    const bool s2 = ((TT) + 2 < NT); \
    /* ---- ph1 ---- */ \
    BARRIER; \
    if (s1) { GB23(NXT, kt1); } \
    a03[0] = DSRI<0>(pAc);    a03[1] = DSRI<1024>(pAc); \
    a03[2] = DSRI<2048>(pAc); a03[3] = DSRI<3072>(pAc); \
    LGKM2; SCHED0; \
    PRIO1; HC(0, 0, a03, 0, b01); PRIO0; SCHED0; \
    LGKM0; SCHED0; \
    PRIO1; HC(2, 0, a03, 2, b01); PRIO0; SCHED0; \
    b23[0] = DSRI<2048>(pBc); b23[1] = DSRI<3072>(pBc); \
    /* ---- ph2 ---- */ \
    BARRIER; \
    if (s1) { GA03(NXT, kt1); GA47(NXT, kt1); } \
    LGKM0; SCHED0; \
    PRIO1; HC(0, 2, a03, 0, b23); PRIO0; SCHED0; \
    a47[0] = DSRI<4096>(pAc); a47[1] = DSRI<5120>(pAc); \
    SCHED0; \
    PRIO1; HC(2, 2, a03, 2, b23); PRIO0; SCHED0; \
    a47[2] = DSRI<6144>(pAc); a47[3] = DSRI<7168>(pAc); \
    /* ---- ph3: counted drain (B01[t+1] confirmed; B23/A[t+1] in flight) */ \
    VMCNT3; \
    BARRIER; \
    LGKM2; SCHED0; \
    PRIO1; HC(4, 0, a47, 0, b01); PRIO0; SCHED0; \
    LGKM0; SCHED0; \
    PRIO1; HC(6, 0, a47, 2, b01); PRIO0; SCHED0; \
    if (s1) { b01[0] = DSRI<0>(pBn); b01[1] = DSRI<1024>(pBn); } \
    /* ---- ph4 ---- */ \
    BARRIER; \
    if (s2) { GB01(CUR, kt2); } \
    PRIO1; HC(4, 2, a47, 0, b23); HC(6, 2, a47, 2, b23); PRIO0; SCHED0; \
    if (s2) { VMCNT1; } else { VMCNT0; } \
}

    for (int t = 0; t < NT; t += 2) {
        TILE_BODY(t,     0, 1, pA0, pB0, pB1);
        TILE_BODY(t + 1, 1, 0, pA1, pB1, pB0);
    }
#undef TILE_BODY

    // ----- epilogue: C/D layout col = lane&15, row = (lane>>4)*4 + j.
    // out = acc_i32 * scale[row] + bias[col]  (acc exact; |acc| < 2^24).
    float bv[4];
#pragma unroll
    for (int n = 0; n < 4; ++n) bv[n] = bias[bcol + wc * 64 + n * 16 + fr];
#pragma unroll
    for (int m = 0; m < 8; ++m) {
        const long rbase = brow + wr * 128 + m * 16 + fq * 4;
        float sc[4];
        *reinterpret_cast<float4*>(sc) =
            *reinterpret_cast<const float4*>(scales + rbase);
#pragma unroll
        for (int n = 0; n < 4; ++n) {
            const long cg = bcol + wc * 64 + n * 16 + fr;
#pragma unroll
            for (int j = 0; j < 4; ++j)
                C[(rbase + j) * (long)N_DIM + cg] =
                    (float)acc[m][n][j] * sc[j] + bv[n];
        }
    }
}

// ---------- naive fallback ----------

__global__ __launch_bounds__(256) void naive_kernel(
    const float* __restrict__ x, const float* __restrict__ w,
    const float* __restrict__ bias, float* __restrict__ out, long total) {
    long gid = (long)blockIdx.x * blockDim.x + threadIdx.x;
    if (gid >= total) return;
    long m = gid / N_DIM, n = gid % N_DIM;
    const float* xr = x + m * (long)K_DIM;
    const float* wr = w + n * (long)K_DIM;
    float s = 0.f;
    for (int k = 0; k < K_DIM; ++k) {
        float wv = wr[k];
        float sg = (wv > 0.f) ? 1.f : ((wv < 0.f) ? -1.f : 0.f);
        s += xr[k] * sg;
    }
    out[gid] = s + bias[n];
}

// ---------- launch ----------

extern "C" void kernel_launch(void* const* d_in, const int* in_sizes, int n_in,
                              void* d_out, int out_size, void* d_ws, size_t ws_size,
                              hipStream_t stream) {
    const float* x    = (const float*)d_in[0];
    const float* w    = (const float*)d_in[1];
    const float* bias = (const float*)d_in[2];
    float* out = (float*)d_out;

    const size_t nA = (size_t)M_DIM * K_DIM;  // 33.5M
    const size_t nB = (size_t)N_DIM * K_DIM;  // 16.8M
    const size_t need = nA + nB + M_DIM * sizeof(float) + 64;

    if (ws_size >= need) {
        signed char* xb = (signed char*)d_ws;
        signed char* wb = xb + nA;
        float* scales = (float*)(wb + nB);

        {
            long nvec16 = (long)(nB / 16);
            cvt_w_i8<<<(int)((nvec16 + 255) / 256), 256, 0, stream>>>(w, wb, nvec16);
        }
        cvt_x_i8<<<M_DIM, 256, 0, stream>>>(x, xb, scales);

        dim3 grid((M_DIM / BM) * (N_DIM / BN));  // 512
        gemm256q<<<grid, 512, 0, stream>>>(xb, wb, scales, bias, out);
    } else {
        long total = (long)M_DIM * N_DIM;
        naive_kernel<<<(int)((total + 255) / 256), 256, 0, stream>>>(x, w, bias, out, total);
    }
}

// Round 19
// 178.461 us; speedup vs baseline: 1.5009x; 1.0097x over previous
//
#include <hip/hip_runtime.h>
#include <hip/hip_bf16.h>

// out[B,S,D_OUT] = x @ sign(W)^T + bias  ==  GEMM M=8192, N=4096, K=4096.
// Round 19: R18 GEMM byte-identical (134us, 0 conflicts, 2.05 POPS i8).
// Change: conversions fused into ONE launch (block-range split) and cvt_x
// made single-pass (16 floats register-cached between max and quantize).
// Non-GEMM time 46us -> predicted ~35us.

#define M_DIM 8192
#define N_DIM 4096
#define K_DIM 4096
#define BM 256
#define BN 256
#define BK 64
#define NT (K_DIM / BK)  // 64

typedef __attribute__((ext_vector_type(4))) int i32x4;

// ---------- fused conversion kernel ----------
// blocks [0, M_DIM): quantize x row b (single pass, register-cached).
// blocks [M_DIM, M_DIM + N_DIM): sign(w) row (b - M_DIM), 16 i8/thread.

__device__ __forceinline__ signed char sgn_i8(float f) {
    return (f > 0.f) ? 1 : ((f < 0.f) ? -1 : 0);
}

__global__ __launch_bounds__(256) void cvt_fused(
    const float* __restrict__ x, const float* __restrict__ w,
    signed char* __restrict__ xb, signed char* __restrict__ wb,
    float* __restrict__ scales) {
    const int b   = blockIdx.x;
    const int tid = threadIdx.x;

    if (b < M_DIM) {
        const float4* xr4 = reinterpret_cast<const float4*>(x + (long)b * K_DIM);
        __shared__ float red[4];
        float4 v[4];
        float mx = 0.f;
#pragma unroll
        for (int i = 0; i < 4; ++i) {
            v[i] = xr4[tid + i * 256];
            mx = fmaxf(mx, fmaxf(fmaxf(fabsf(v[i].x), fabsf(v[i].y)),
                                 fmaxf(fabsf(v[i].z), fabsf(v[i].w))));
        }
#pragma unroll
        for (int o = 1; o < 64; o <<= 1) mx = fmaxf(mx, __shfl_xor(mx, o));
        if ((tid & 63) == 0) red[tid >> 6] = mx;
        __syncthreads();
        float rmax = fmaxf(fmaxf(red[0], red[1]), fmaxf(red[2], red[3]));
        const float inv = (rmax > 0.f) ? (127.f / rmax) : 0.f;

        char4* qr = reinterpret_cast<char4*>(xb + (long)b * K_DIM);
#pragma unroll
        for (int i = 0; i < 4; ++i) {
            char4 c;
            c.x = (signed char)__float2int_rn(fminf(fmaxf(v[i].x * inv, -127.f), 127.f));
            c.y = (signed char)__float2int_rn(fminf(fmaxf(v[i].y * inv, -127.f), 127.f));
            c.z = (signed char)__float2int_rn(fminf(fmaxf(v[i].z * inv, -127.f), 127.f));
            c.w = (signed char)__float2int_rn(fminf(fmaxf(v[i].w * inv, -127.f), 127.f));
            qr[tid + i * 256] = c;
        }
        if (tid == 0) scales[b] = (rmax > 0.f) ? (rmax * (1.f / 127.f)) : 0.f;
    } else {
        // one block per W row: 4096 floats -> 4096 i8, 16 per thread
        const long i = (long)(b - M_DIM) * 256 + tid;  // vec16 index
        const float4* p = reinterpret_cast<const float4*>(w) + i * 4;
        int4 r;
        signed char* rc = (signed char*)&r;
#pragma unroll
        for (int k = 0; k < 4; ++k) {
            float4 vv = p[k];
            rc[k * 4 + 0] = sgn_i8(vv.x);
            rc[k * 4 + 1] = sgn_i8(vv.y);
            rc[k * 4 + 2] = sgn_i8(vv.z);
            rc[k * 4 + 3] = sgn_i8(vv.w);
        }
        reinterpret_cast<int4*>(wb)[i] = r;
    }
}

// ---------- async global->LDS ----------

__device__ __forceinline__ void GL16(const void* g, void* l) {
    __builtin_amdgcn_global_load_lds(
        (const __attribute__((address_space(1))) unsigned int*)g,
        (__attribute__((address_space(3))) unsigned int*)l, 16, 0, 0);
}

// ---------- inline-asm ds_read_b128 (i32x4) ----------

template<int OFS>
__device__ __forceinline__ i32x4 DSRI(const signed char* p) {
    i32x4 r;
    auto lp = (const __attribute__((address_space(3))) signed char*)p;
    asm volatile("ds_read_b128 %0, %1 offset:%2"
                 : "=&v"(r) : "v"(lp), "i"(OFS));
    return r;
}

#define BARRIER asm volatile("s_barrier" ::: "memory")
#define VMCNT0  asm volatile("s_waitcnt vmcnt(0)" ::: "memory")
#define VMCNT1  asm volatile("s_waitcnt vmcnt(1)" ::: "memory")
#define VMCNT3  asm volatile("s_waitcnt vmcnt(3)" ::: "memory")
#define LGKM0   asm volatile("s_waitcnt lgkmcnt(0)" ::: "memory")
#define LGKM2   asm volatile("s_waitcnt lgkmcnt(2)" ::: "memory")
#define SCHED0  __builtin_amdgcn_sched_barrier(0)
#define PRIO1   __builtin_amdgcn_s_setprio(1)
#define PRIO0   __builtin_amdgcn_s_setprio(0)

// 4-MFMA cell: 2 m-frags x 2 n-frags, K=64 in one MFMA each.
#define HC(MB, NB, Af, AOFS, Bf) \
    _Pragma("unroll") for (int m_ = 0; m_ < 2; ++m_) \
    _Pragma("unroll") for (int n_ = 0; n_ < 2; ++n_) \
        acc[(MB) + m_][(NB) + n_] = __builtin_amdgcn_mfma_i32_16x16x64_i8( \
            Af[(AOFS) + m_], Bf[n_], acc[(MB) + m_][(NB) + n_], 0, 0, 0)

// ---------- 256x256 4-phase i8 GEMM (R18, byte-identical) ----------
// 512 thr = 8 waves (2M x 4N); wave out 128x64 = 8x4 16x16 frags; 32 MFMA/tile.
// LDS: As/Bs [2][256 rows][64B] = 64 KiB total (2 blocks/CU co-resident).
// Swizzle: row r's logical 16B-chunk g at phys g ^ ((r>>1)&3); staged via
// inverse-swizzled global cols (linear GL16 dest), read with the same XOR.
// Per K-tile t (CUR=t&1):
//  ph1: bar | stage B23(t+1)->NXT | rd a03 x4 | LGKM(2) [b01+a03(0,1)]
//       | 4 MFMA | LGKM(0) | 4 MFMA | rd b23 x2
//  ph2: bar | stage A03+A47(t+1)->NXT | LGKM(0) [b23] | 4 MFMA | rd a47(0,1)
//       | 4 MFMA | rd a47(2,3)
//  ph3: vmcnt(3) [confirms B01(t+1)] | bar | LGKM(2) [a47(0,1)] | 4 MFMA
//       | LGKM(0) | 4 MFMA | rd b01(t+1) x2
//  ph4: bar | stage B01(t+2)->CUR | 8 MFMA | vmcnt(s2?1:0)
// vmcnt ledger (in-order): ph3(t): B01[t+1](1)+B23[t+1](1)+A[t+1](2)=4 ->
// vmcnt(3) drains B01[t+1]. ph4(t) end: B23+A[t+1]+B01[t+2]=4 -> vmcnt(1)
// drains B23+A[t+1]. Tail s2=false -> vmcnt(0).

__global__ __launch_bounds__(512, 2) void gemm256q(
    const signed char* __restrict__ A,   // [M][K] i8 (quantized x)
    const signed char* __restrict__ Bt,  // [N][K] i8 (sign weights)
    const float* __restrict__ scales,    // [M] rowmax/127
    const float* __restrict__ bias,      // [N]
    float* __restrict__ C)               // [M][N] fp32
{
    __shared__ __align__(16) signed char As[2][BM * BK];  // 2 x 16 KiB
    __shared__ __align__(16) signed char Bs[2][BN * BK];  // 2 x 16 KiB

    const int tid  = threadIdx.x;
    const int lane = tid & 63;
    const int w    = tid >> 6;
    const int wr   = w >> 2;
    const int wc   = w & 3;

    // T1: XCD-aware bijective swizzle (grid = 512, divisible by 8)
    int bid = blockIdx.x;
    const int cpx = gridDim.x >> 3;
    bid = (bid & 7) * cpx + (bid >> 3);
    const int ntile = N_DIM / BN;  // 16
    const long brow = (long)(bid / ntile) * BM;
    const long bcol = (long)(bid % ntile) * BN;

    // ----- staging: each GL16/wave = 16 rows x 64B; lane l -> row l>>2,
    // phys chunk l&3; global col chunk g = (l&3) ^ ((l>>3)&3)  [row>>1 swz].
    const int lrow  = lane >> 2;
    const int gcol  = ((lane & 3) ^ ((lane >> 3) & 3)) * 16;  // i8 elements
    const int rA03u = (w >> 2) * 128 + (w & 3) * 16;          // wave-uniform
    const int rB01u = (w >> 1) * 64 + (w & 1) * 16;
    const long gA03 = brow + rA03u + lrow;
    const long gB01 = bcol + rB01u + lrow;

#define GA03(BUF, KT) GL16(A  + (gA03)      * (long)K_DIM + (gcol + (KT)), &As[BUF][(rA03u)      * 64])
#define GA47(BUF, KT) GL16(A  + (gA03 + 64) * (long)K_DIM + (gcol + (KT)), &As[BUF][(rA03u + 64) * 64])
#define GB01(BUF, KT) GL16(Bt + (gB01)      * (long)K_DIM + (gcol + (KT)), &Bs[BUF][(rB01u)      * 64])
#define GB23(BUF, KT) GL16(Bt + (gB01 + 32) * (long)K_DIM + (gcol + (KT)), &Bs[BUF][(rB01u + 32) * 64])

    // ----- fragment reads: row = base + (lane&15), k-chunk g = lane>>4,
    // phys chunk = g ^ ((row>>1)&3) = (lane>>4) ^ ((lane>>1)&3)  [base%16==0].
    const int fr = lane & 15;
    const int fq = lane >> 4;
    const int pch = (fq ^ ((lane >> 1) & 3)) * 16;  // bytes
    const int aoffB = (wr * 128 + fr) * 64 + pch;
    const int boffB = (wc * 64 + fr) * 64 + pch;

    const signed char* pA0 = &As[0][aoffB];
    const signed char* pA1 = &As[1][aoffB];
    const signed char* pB0 = &Bs[0][boffB];
    const signed char* pB1 = &Bs[1][boffB];

    i32x4 acc[8][4];
#pragma unroll
    for (int m = 0; m < 8; ++m)
#pragma unroll
        for (int n = 0; n < 4; ++n) acc[m][n] = (i32x4){0, 0, 0, 0};

    i32x4 a03[4], a47[4], b01[2], b23[2];

    // ----- prologue: tile0 (4 GL16) + tile1's B01 (1 GL16) -----
    GA03(0, 0); GA47(0, 0); GB01(0, 0); GB23(0, 0);
    GB01(1, BK);
    VMCNT0;
    BARRIER;
    b01[0] = DSRI<0>(pB0);
    b01[1] = DSRI<1024>(pB0);

#define TILE_BODY(TT, CUR, NXT, pAc, pBc, pBn) { \
    const long kt1 = (long)((TT) + 1) * BK; \
    const long kt2 = (long)((TT) + 2) * BK; \
    const bool s1 = ((TT) + 1 < NT); \
    const bool s2 = ((TT) + 2 < NT); \
    /* ---- ph1 ---- */ \
    BARRIER; \
    if (s1) { GB23(NXT, kt1); } \
    a03[0] = DSRI<0>(pAc);    a03[1] = DSRI<1024>(pAc); \
    a03[2] = DSRI<2048>(pAc); a03[3] = DSRI<3072>(pAc); \
    LGKM2; SCHED0; \
    PRIO1; HC(0, 0, a03, 0, b01); PRIO0; SCHED0; \
    LGKM0; SCHED0; \
    PRIO1; HC(2, 0, a03, 2, b01); PRIO0; SCHED0; \
    b23[0] = DSRI<2048>(pBc); b23[1] = DSRI<3072>(pBc); \
    /* ---- ph2 ---- */ \
    BARRIER; \
    if (s1) { GA03(NXT, kt1); GA47(NXT, kt1); } \
    LGKM0; SCHED0; \
    PRIO1; HC(0, 2, a03, 0, b23); PRIO0; SCHED0; \
    a47[0] = DSRI<4096>(pAc); a47[1] = DSRI<5120>(pAc); \
    SCHED0; \
    PRIO1; HC(2, 2, a03, 2, b23); PRIO0; SCHED0; \
    a47[2] = DSRI<6144>(pAc); a47[3] = DSRI<7168>(pAc); \
    /* ---- ph3: counted drain (B01[t+1] confirmed; B23/A[t+1] in flight) */ \
    VMCNT3; \
    BARRIER; \
    LGKM2; SCHED0; \
    PRIO1; HC(4, 0, a47, 0, b01); PRIO0; SCHED0; \
    LGKM0; SCHED0; \
    PRIO1; HC(6, 0, a47, 2, b01); PRIO0; SCHED0; \
    if (s1) { b01[0] = DSRI<0>(pBn); b01[1] = DSRI<1024>(pBn); } \
    /* ---- ph4 ---- */ \
    BARRIER; \
    if (s2) { GB01(CUR, kt2); } \
    PRIO1; HC(4, 2, a47, 0, b23); HC(6, 2, a47, 2, b23); PRIO0; SCHED0; \
    if (s2) { VMCNT1; } else { VMCNT0; } \
}

    for (int t = 0; t < NT; t += 2) {
        TILE_BODY(t,     0, 1, pA0, pB0, pB1);
        TILE_BODY(t + 1, 1, 0, pA1, pB1, pB0);
    }
#undef TILE_BODY

    // ----- epilogue: C/D layout col = lane&15, row = (lane>>4)*4 + j.
    // out = acc_i32 * scale[row] + bias[col]  (acc exact; |acc| < 2^24).
    float bv[4];
#pragma unroll
    for (int n = 0; n < 4; ++n) bv[n] = bias[bcol + wc * 64 + n * 16 + fr];
#pragma unroll
    for (int m = 0; m < 8; ++m) {
        const long rbase = brow + wr * 128 + m * 16 + fq * 4;
        float sc[4];
        *reinterpret_cast<float4*>(sc) =
            *reinterpret_cast<const float4*>(scales + rbase);
#pragma unroll
        for (int n = 0; n < 4; ++n) {
            const long cg = bcol + wc * 64 + n * 16 + fr;
#pragma unroll
            for (int j = 0; j < 4; ++j)
                C[(rbase + j) * (long)N_DIM + cg] =
                    (float)acc[m][n][j] * sc[j] + bv[n];
        }
    }
}

// ---------- naive fallback ----------

__global__ __launch_bounds__(256) void naive_kernel(
    const float* __restrict__ x, const float* __restrict__ w,
    const float* __restrict__ bias, float* __restrict__ out, long total) {
    long gid = (long)blockIdx.x * blockDim.x + threadIdx.x;
    if (gid >= total) return;
    long m = gid / N_DIM, n = gid % N_DIM;
    const float* xr = x + m * (long)K_DIM;
    const float* wr = w + n * (long)K_DIM;
    float s = 0.f;
    for (int k = 0; k < K_DIM; ++k) {
        float wv = wr[k];
        float sg = (wv > 0.f) ? 1.f : ((wv < 0.f) ? -1.f : 0.f);
        s += xr[k] * sg;
    }
    out[gid] = s + bias[n];
}

// ---------- launch ----------

extern "C" void kernel_launch(void* const* d_in, const int* in_sizes, int n_in,
                              void* d_out, int out_size, void* d_ws, size_t ws_size,
                              hipStream_t stream) {
    const float* x    = (const float*)d_in[0];
    const float* w    = (const float*)d_in[1];
    const float* bias = (const float*)d_in[2];
    float* out = (float*)d_out;

    const size_t nA = (size_t)M_DIM * K_DIM;  // 33.5M
    const size_t nB = (size_t)N_DIM * K_DIM;  // 16.8M
    const size_t need = nA + nB + M_DIM * sizeof(float) + 64;

    if (ws_size >= need) {
        signed char* xb = (signed char*)d_ws;
        signed char* wb = xb + nA;
        float* scales = (float*)(wb + nB);

        cvt_fused<<<M_DIM + N_DIM, 256, 0, stream>>>(x, w, xb, wb, scales);

        dim3 grid((M_DIM / BM) * (N_DIM / BN));  // 512
        gemm256q<<<grid, 512, 0, stream>>>(xb, wb, scales, bias, out);
    } else {
        long total = (long)M_DIM * N_DIM;
        naive_kernel<<<(int)((total + 255) / 256), 256, 0, stream>>>(x, w, bias, out, total);
    }
}